// Round 5
// baseline (252.794 us; speedup 1.0000x reference)
//
#include <hip/hip_runtime.h>

// C3 partial conv: x[64,6,256,256] f32, W[16,6,5,5] f32 (sparse connection table
// handled by iterating connected channels only), b[16]. out[64,16,252,252] f32.
// out = 1.7159 * tanh((2/3) * (conv_valid(x, W) + b))
//
// Round 8: register-pin attack. r7 (rolled switch, ~10KB code) fixed the L1I
// thrash (1146->241us) but VGPR_Count=40 proves the win[6][5] window was
// demoted to per-case LDS re-reads (acc16+addr~20 alone = 40; win's 30 regs
// are missing). Those are unmergeable ds_read_b32 storms drained by the same
// lgkmcnt(0) as the weight s_loads before every FMA block -> ~30% real VALU
// port utilization. Fix: asm volatile("" : "+v") pin on each win element
// after load -- makes the value opaque so the compiler CANNOT rematerialize
// from LDS; it must hold it in a VGPR. Everything else identical to r7.
// NO min-waves launch_bounds arg (hard VGPR clamp -> scratch disaster, r2/r4).

__device__ __forceinline__ void conv25(const float* __restrict__ wp,
                                       const float (&win)[6][5],
                                       float& a0, float& a1) {
    #pragma unroll
    for (int ky = 0; ky < 5; ++ky)
        #pragma unroll
        for (int kx = 0; kx < 5; ++kx) {
            const float wv = wp[ky * 5 + kx];   // uniform -> s_load batch
            a0 = fmaf(win[ky + 0][kx], wv, a0);
            a1 = fmaf(win[ky + 1][kx], wv, a1);
        }
}

__global__ __launch_bounds__(256) void c3_partial_conv_kernel(
    const float* __restrict__ x,   // [64,6,256,256]
    const float* __restrict__ W,   // [16,6,5,5]
    const float* __restrict__ b,   // [16]
    float* __restrict__ out)       // [64,16,252,252]
{
    // Reverse maps per group: for input channel c, the output channels in
    // this group that consume it (count arrays give real lengths).
    constexpr int G0N[6] = {4, 5, 5, 5, 4, 3};
    constexpr int G0O[6][5] = {
        {0, 4, 5, 6, 0},
        {0, 1, 5, 6, 7},
        {0, 1, 2, 6, 7},
        {1, 2, 3, 6, 7},
        {2, 3, 4, 7, 0},
        {3, 4, 5, 0, 0}};
    constexpr int G1N[6] = {6, 5, 5, 5, 6, 7};
    constexpr int G1O[6][7] = {
        {9, 10, 11, 12, 14, 15, 8},
        {10, 11, 12, 13, 15, 8, 8},
        {8, 11, 13, 14, 15, 8, 8},
        {8, 9, 12, 14, 15, 8, 8},
        {8, 9, 10, 12, 13, 15, 8},
        {8, 9, 10, 11, 13, 14, 15}};

    // Input tile: 6 ch x 20 rows x 36 cols (row stride 40 floats, 16B-aligned).
    __shared__ float lds[6][20][40];  // 19200 B

    const int tx  = threadIdx.x;   // 0..31 -> output col within tile
    const int ty  = threadIdx.y;   // 0..7  -> output row pair
    const int tid = ty * 32 + tx;

    const int tileX = blockIdx.x << 5;   // 0..224
    const int tileY = blockIdx.y << 4;   // 0..240
    const int batch = blockIdx.z;

    const float* xb = x + (size_t)batch * 6 * 256 * 256;

    // ---- stage input tile: float4 chunks. 6*20*9 = 1080 chunks ----
    for (int i = tid; i < 1080; i += 256) {
        int c   = i / 180;
        int rem = i - c * 180;
        int r   = rem / 9;
        int q   = rem - r * 9;
        int gr  = tileY + r;
        int gc0 = tileX + (q << 2);
        float4 v = make_float4(0.f, 0.f, 0.f, 0.f);
        if (gr < 256 && gc0 < 256)    // chunk fully in-bounds or fully out
            v = *reinterpret_cast<const float4*>(&xb[(c * 256 + gr) * 256 + gc0]);
        *reinterpret_cast<float4*>(&lds[c][r][q << 2]) = v;
    }
    __syncthreads();

    const int row0 = ty << 1;            // local output row base (0..14)
    const int ocol = tileX + tx;
    float* ob = out + (size_t)batch * 16 * 252 * 252;
    const bool colok = (ocol < 252);

    // ================= group 0 : out channels 0..7 =================
    {
        float acc[8][2];
        #pragma unroll
        for (int o = 0; o < 8; ++o) {
            float bv = b[o];
            acc[o][0] = bv; acc[o][1] = bv;
        }

        #pragma unroll 1
        for (int c = 0; c < 6; ++c) {
            float win[6][5];
            #pragma unroll
            for (int r = 0; r < 6; ++r)
                #pragma unroll
                for (int j = 0; j < 5; ++j) {
                    win[r][j] = lds[c][row0 + r][tx + j];
                    // Pin to a VGPR: value becomes opaque, compiler cannot
                    // rematerialize it from LDS inside the switch cases.
                    asm volatile("" : "+v"(win[r][j]));
                }

            const int n = G0N[c];
            #pragma unroll 1
            for (int oi = 0; oi < n; ++oi) {
                switch (G0O[c][oi]) {      // uniform scalar branch
                    case 0: conv25(W + (0 * 6 + c) * 25, win, acc[0][0], acc[0][1]); break;
                    case 1: conv25(W + (1 * 6 + c) * 25, win, acc[1][0], acc[1][1]); break;
                    case 2: conv25(W + (2 * 6 + c) * 25, win, acc[2][0], acc[2][1]); break;
                    case 3: conv25(W + (3 * 6 + c) * 25, win, acc[3][0], acc[3][1]); break;
                    case 4: conv25(W + (4 * 6 + c) * 25, win, acc[4][0], acc[4][1]); break;
                    case 5: conv25(W + (5 * 6 + c) * 25, win, acc[5][0], acc[5][1]); break;
                    case 6: conv25(W + (6 * 6 + c) * 25, win, acc[6][0], acc[6][1]); break;
                    case 7: conv25(W + (7 * 6 + c) * 25, win, acc[7][0], acc[7][1]); break;
                    default: break;
                }
            }
        }

        if (colok) {
            #pragma unroll
            for (int o = 0; o < 8; ++o)
                #pragma unroll
                for (int dy = 0; dy < 2; ++dy) {
                    int orow = tileY + row0 + dy;
                    if (orow < 252) {
                        float z = acc[o][dy] * (2.0f / 3.0f);
                        float e = __expf(2.0f * z);              // v_exp_f32 path
                        float rr = __builtin_amdgcn_rcpf(e + 1.0f);
                        ob[(o * 252 + orow) * 252 + ocol] = 1.7159f * (1.0f - 2.0f * rr);
                    }
                }
        }
    }

    // keep the two groups' live ranges separate
    __builtin_amdgcn_sched_barrier(0);

    // ================= group 1 : out channels 8..15 =================
    {
        float acc[8][2];
        #pragma unroll
        for (int o = 0; o < 8; ++o) {
            float bv = b[8 + o];
            acc[o][0] = bv; acc[o][1] = bv;
        }

        #pragma unroll 1
        for (int c = 0; c < 6; ++c) {
            float win[6][5];
            #pragma unroll
            for (int r = 0; r < 6; ++r)
                #pragma unroll
                for (int j = 0; j < 5; ++j) {
                    win[r][j] = lds[c][row0 + r][tx + j];
                    asm volatile("" : "+v"(win[r][j]));
                }

            const int n = G1N[c];
            #pragma unroll 1
            for (int oi = 0; oi < n; ++oi) {
                switch (G1O[c][oi]) {      // uniform scalar branch
                    case  8: conv25(W + ( 8 * 6 + c) * 25, win, acc[0][0], acc[0][1]); break;
                    case  9: conv25(W + ( 9 * 6 + c) * 25, win, acc[1][0], acc[1][1]); break;
                    case 10: conv25(W + (10 * 6 + c) * 25, win, acc[2][0], acc[2][1]); break;
                    case 11: conv25(W + (11 * 6 + c) * 25, win, acc[3][0], acc[3][1]); break;
                    case 12: conv25(W + (12 * 6 + c) * 25, win, acc[4][0], acc[4][1]); break;
                    case 13: conv25(W + (13 * 6 + c) * 25, win, acc[5][0], acc[5][1]); break;
                    case 14: conv25(W + (14 * 6 + c) * 25, win, acc[6][0], acc[6][1]); break;
                    case 15: conv25(W + (15 * 6 + c) * 25, win, acc[7][0], acc[7][1]); break;
                    default: break;
                }
            }
        }

        if (colok) {
            #pragma unroll
            for (int o = 0; o < 8; ++o)
                #pragma unroll
                for (int dy = 0; dy < 2; ++dy) {
                    int orow = tileY + row0 + dy;
                    if (orow < 252) {
                        float z = acc[o][dy] * (2.0f / 3.0f);
                        float e = __expf(2.0f * z);
                        float rr = __builtin_amdgcn_rcpf(e + 1.0f);
                        ob[((8 + o) * 252 + orow) * 252 + ocol] = 1.7159f * (1.0f - 2.0f * rr);
                    }
                }
        }
    }
}

extern "C" void kernel_launch(void* const* d_in, const int* in_sizes, int n_in,
                              void* d_out, int out_size, void* d_ws, size_t ws_size,
                              hipStream_t stream) {
    const float* x = (const float*)d_in[0];
    const float* W = (const float*)d_in[1];
    const float* b = (const float*)d_in[2];
    float* out = (float*)d_out;

    dim3 grid(8, 16, 64);   // 8 col-tiles x 16 row-tiles x 64 batches
    dim3 block(32, 8);
    hipLaunchKernelGGL(c3_partial_conv_kernel, grid, block, 0, stream, x, W, b, out);
}

// Round 6
// 229.736 us; speedup vs baseline: 1.1004x; 1.1004x over previous
//
#include <hip/hip_runtime.h>

// C3 partial conv: x[64,6,256,256] f32, W[16,6,5,5] f32 (sparse connection table
// handled by iterating connected channels only), b[16]. out[64,16,252,252] f32.
// out = 1.7159 * tanh((2/3) * (conv_valid(x, W) + b))
//
// Round 9: rolled switch (r7, fixes L1I thrash) x 4 rows/thread (r6's
// arithmetic intensity, whose failure was code SIZE not structure).
// r8's pin test proved win[][] was already register-resident (AGPR-parked;
// VGPR_Count shows arch-VGPRs only) -> remaining stall is per-case weight
// s_load latency: rolled switch can't prefetch case k+1's weights until the
// branch resolves, so each case is {branch, ~150cy s_load, 100cy FMA}.
// 4 rows/thread doubles FMA per weight batch (200cy issue per case) and
// halves window-read + staging + epilogue cost per output. Code ~20KB total,
// ~8KB hot per group -> fits 32KB L1I. LDS 34.6KB -> 4 blocks/CU.
// NO min-waves launch_bounds arg (hard VGPR clamp -> scratch, r2/r4).
// No asm pins (r8: no effect on alloc, slight perf cost).

__device__ __forceinline__ void conv50(const float* __restrict__ wp,
                                       const float (&win)[8][5],
                                       float& a0, float& a1, float& a2, float& a3) {
    #pragma unroll
    for (int ky = 0; ky < 5; ++ky)
        #pragma unroll
        for (int kx = 0; kx < 5; ++kx) {
            const float wv = wp[ky * 5 + kx];   // uniform -> s_load batch
            a0 = fmaf(win[ky + 0][kx], wv, a0);
            a1 = fmaf(win[ky + 1][kx], wv, a1);
            a2 = fmaf(win[ky + 2][kx], wv, a2);
            a3 = fmaf(win[ky + 3][kx], wv, a3);
        }
}

__global__ __launch_bounds__(256) void c3_partial_conv_kernel(
    const float* __restrict__ x,   // [64,6,256,256]
    const float* __restrict__ W,   // [16,6,5,5]
    const float* __restrict__ b,   // [16]
    float* __restrict__ out)       // [64,16,252,252]
{
    // Reverse maps per group: for input channel c, the output channels in
    // this group that consume it (count arrays give real lengths).
    constexpr int G0N[6] = {4, 5, 5, 5, 4, 3};
    constexpr int G0O[6][5] = {
        {0, 4, 5, 6, 0},
        {0, 1, 5, 6, 7},
        {0, 1, 2, 6, 7},
        {1, 2, 3, 6, 7},
        {2, 3, 4, 7, 0},
        {3, 4, 5, 0, 0}};
    constexpr int G1N[6] = {6, 5, 5, 5, 6, 7};
    constexpr int G1O[6][7] = {
        {9, 10, 11, 12, 14, 15, 8},
        {10, 11, 12, 13, 15, 8, 8},
        {8, 11, 13, 14, 15, 8, 8},
        {8, 9, 12, 14, 15, 8, 8},
        {8, 9, 10, 12, 13, 15, 8},
        {8, 9, 10, 11, 13, 14, 15}};

    // Input tile: 6 ch x 36 rows x 36 cols (row stride 40 floats, 16B-aligned).
    __shared__ float lds[6][36][40];  // 34560 B -> 4 blocks/CU

    const int tx  = threadIdx.x;   // 0..31 -> output col within tile
    const int ty  = threadIdx.y;   // 0..7  -> output row quad
    const int tid = ty * 32 + tx;

    const int tileX = blockIdx.x << 5;   // 0..224
    const int tileY = blockIdx.y << 5;   // 0..224
    const int batch = blockIdx.z;

    const float* xb = x + (size_t)batch * 6 * 256 * 256;

    // ---- stage input tile: float4 chunks. 6*36*9 = 1944 chunks ----
    for (int i = tid; i < 1944; i += 256) {
        int c   = i / 324;            // 36 rows * 9 chunks
        int rem = i - c * 324;
        int r   = rem / 9;
        int q   = rem - r * 9;
        int gr  = tileY + r;
        int gc0 = tileX + (q << 2);
        float4 v = make_float4(0.f, 0.f, 0.f, 0.f);
        if (gr < 256 && gc0 < 256)    // chunk fully in-bounds or fully out
            v = *reinterpret_cast<const float4*>(&xb[(c * 256 + gr) * 256 + gc0]);
        *reinterpret_cast<float4*>(&lds[c][r][q << 2]) = v;
    }
    __syncthreads();

    const int row0 = ty << 2;            // local output row base (0..28)
    const int ocol = tileX + tx;
    float* ob = out + (size_t)batch * 16 * 252 * 252;
    const bool colok = (ocol < 252);

    // ================= group 0 : out channels 0..7 =================
    {
        float acc[8][4];
        #pragma unroll
        for (int o = 0; o < 8; ++o) {
            float bv = b[o];
            #pragma unroll
            for (int dy = 0; dy < 4; ++dy) acc[o][dy] = bv;
        }

        #pragma unroll 1
        for (int c = 0; c < 6; ++c) {
            float win[8][5];
            #pragma unroll
            for (int r = 0; r < 8; ++r)
                #pragma unroll
                for (int j = 0; j < 5; ++j)
                    win[r][j] = lds[c][row0 + r][tx + j];

            const int n = G0N[c];
            #pragma unroll 1
            for (int oi = 0; oi < n; ++oi) {
                switch (G0O[c][oi]) {      // uniform scalar branch
                    case 0: conv50(W + (0 * 6 + c) * 25, win, acc[0][0], acc[0][1], acc[0][2], acc[0][3]); break;
                    case 1: conv50(W + (1 * 6 + c) * 25, win, acc[1][0], acc[1][1], acc[1][2], acc[1][3]); break;
                    case 2: conv50(W + (2 * 6 + c) * 25, win, acc[2][0], acc[2][1], acc[2][2], acc[2][3]); break;
                    case 3: conv50(W + (3 * 6 + c) * 25, win, acc[3][0], acc[3][1], acc[3][2], acc[3][3]); break;
                    case 4: conv50(W + (4 * 6 + c) * 25, win, acc[4][0], acc[4][1], acc[4][2], acc[4][3]); break;
                    case 5: conv50(W + (5 * 6 + c) * 25, win, acc[5][0], acc[5][1], acc[5][2], acc[5][3]); break;
                    case 6: conv50(W + (6 * 6 + c) * 25, win, acc[6][0], acc[6][1], acc[6][2], acc[6][3]); break;
                    case 7: conv50(W + (7 * 6 + c) * 25, win, acc[7][0], acc[7][1], acc[7][2], acc[7][3]); break;
                    default: break;
                }
            }
        }

        if (colok) {
            #pragma unroll
            for (int o = 0; o < 8; ++o)
                #pragma unroll
                for (int dy = 0; dy < 4; ++dy) {
                    int orow = tileY + row0 + dy;
                    if (orow < 252) {
                        float z = acc[o][dy] * (2.0f / 3.0f);
                        float e = __expf(2.0f * z);              // v_exp_f32 path
                        float rr = __builtin_amdgcn_rcpf(e + 1.0f);
                        ob[(o * 252 + orow) * 252 + ocol] = 1.7159f * (1.0f - 2.0f * rr);
                    }
                }
        }
    }

    // keep the two groups' live ranges separate
    __builtin_amdgcn_sched_barrier(0);

    // ================= group 1 : out channels 8..15 =================
    {
        float acc[8][4];
        #pragma unroll
        for (int o = 0; o < 8; ++o) {
            float bv = b[8 + o];
            #pragma unroll
            for (int dy = 0; dy < 4; ++dy) acc[o][dy] = bv;
        }

        #pragma unroll 1
        for (int c = 0; c < 6; ++c) {
            float win[8][5];
            #pragma unroll
            for (int r = 0; r < 8; ++r)
                #pragma unroll
                for (int j = 0; j < 5; ++j)
                    win[r][j] = lds[c][row0 + r][tx + j];

            const int n = G1N[c];
            #pragma unroll 1
            for (int oi = 0; oi < n; ++oi) {
                switch (G1O[c][oi]) {      // uniform scalar branch
                    case  8: conv50(W + ( 8 * 6 + c) * 25, win, acc[0][0], acc[0][1], acc[0][2], acc[0][3]); break;
                    case  9: conv50(W + ( 9 * 6 + c) * 25, win, acc[1][0], acc[1][1], acc[1][2], acc[1][3]); break;
                    case 10: conv50(W + (10 * 6 + c) * 25, win, acc[2][0], acc[2][1], acc[2][2], acc[2][3]); break;
                    case 11: conv50(W + (11 * 6 + c) * 25, win, acc[3][0], acc[3][1], acc[3][2], acc[3][3]); break;
                    case 12: conv50(W + (12 * 6 + c) * 25, win, acc[4][0], acc[4][1], acc[4][2], acc[4][3]); break;
                    case 13: conv50(W + (13 * 6 + c) * 25, win, acc[5][0], acc[5][1], acc[5][2], acc[5][3]); break;
                    case 14: conv50(W + (14 * 6 + c) * 25, win, acc[6][0], acc[6][1], acc[6][2], acc[6][3]); break;
                    case 15: conv50(W + (15 * 6 + c) * 25, win, acc[7][0], acc[7][1], acc[7][2], acc[7][3]); break;
                    default: break;
                }
            }
        }

        if (colok) {
            #pragma unroll
            for (int o = 0; o < 8; ++o)
                #pragma unroll
                for (int dy = 0; dy < 4; ++dy) {
                    int orow = tileY + row0 + dy;
                    if (orow < 252) {
                        float z = acc[o][dy] * (2.0f / 3.0f);
                        float e = __expf(2.0f * z);
                        float rr = __builtin_amdgcn_rcpf(e + 1.0f);
                        ob[((8 + o) * 252 + orow) * 252 + ocol] = 1.7159f * (1.0f - 2.0f * rr);
                    }
                }
        }
    }
}

extern "C" void kernel_launch(void* const* d_in, const int* in_sizes, int n_in,
                              void* d_out, int out_size, void* d_ws, size_t ws_size,
                              hipStream_t stream) {
    const float* x = (const float*)d_in[0];
    const float* W = (const float*)d_in[1];
    const float* b = (const float*)d_in[2];
    float* out = (float*)d_out;

    dim3 grid(8, 8, 64);   // 8 col-tiles x 8 row-tiles x 64 batches
    dim3 block(32, 8);
    hipLaunchKernelGGL(c3_partial_conv_kernel, grid, block, 0, stream, x, W, b, out);
}